// Round 2
// baseline (492.832 us; speedup 1.0000x reference)
//
#include <hip/hip_runtime.h>

// EnsembleFC: out = relu(relu(x@W1+b1)@W2+b2)@W3+b3, E=16, B=8192, D=H=512, DOUT=1
// bf16 hi/lo split (3-MFMA emulated fp32), fully fused, 32x32x16 MFMA.
//  - prep kernels split x/W1/W2 into hi/lo bf16 packed in MFMA fragment order
//  - fused kernel: block = (e, 64-row batch tile); h1 in LDS (XOR-swizzled r&15),
//    h2 in accumulators, W streamed global->VGPR with 1-deep double buffer.

#define E_N   16
#define DIN   512
#define HID   512
#define BATCH 8192
#define BT    64
#define NBT   (BATCH / BT)   // 128
#define NBLK  (E_N * NBT)    // 2048

typedef __attribute__((ext_vector_type(8))) short bf16x8;
typedef __attribute__((ext_vector_type(16))) float f32x16;

#define IMG_BYTES   131072                      // [2 s][64 r][1024 B], swizzled
#define XPACK_BYTES ((size_t)NBT * IMG_BYTES)   // 16.78 MB
#define WP_PER_E    (1 << 20)                   // [16 nt][16 kb][4 frag][64 lane][16 B] = 1 MB
#define WP_BYTES    ((size_t)E_N * WP_PER_E)    // 16.78 MB

__device__ __forceinline__ short f2bf(float f) {
  unsigned u = __builtin_bit_cast(unsigned, f);
  u += 0x7fffu + ((u >> 16) & 1u);              // RTNE
  return (short)(u >> 16);
}
__device__ __forceinline__ float bf2f(short s) {
  unsigned u = ((unsigned)(unsigned short)s) << 16;
  return __builtin_bit_cast(float, u);
}

// ---- prep: split x into hi/lo bf16 images, swizzle (r&15)<<4 baked in ----
__global__ void pack_x_kernel(const float* __restrict__ x, char* __restrict__ xp) {
  int t  = blockIdx.x * blockDim.x + threadIdx.x;  // 524288 threads
  int b  = t >> 6;
  int c8 = (t & 63) << 3;
  const float* src = x + (size_t)b * DIN + c8;
  bf16x8 hi, lo;
#pragma unroll
  for (int j = 0; j < 8; ++j) {
    float v = src[j];
    short h = f2bf(v);
    hi[j] = h;
    lo[j] = f2bf(v - bf2f(h));
  }
  int btile = b >> 6, r = b & 63;
  char* img = xp + (size_t)btile * IMG_BYTES;
  int inrow = (c8 << 1) ^ ((r & 15) << 4);
  *(bf16x8*)(img + (r << 10) + inrow) = hi;
  *(bf16x8*)(img + 65536 + (r << 10) + inrow) = lo;
}

// ---- prep: split W into hi/lo bf16 B-fragments (32x32x16 layout) ----
// B-frag element: W[e][kb*32 + kk*16 + (lane>>5)*8 + j][nt*32 + (lane&31)]
// dst: [e][nt(16)][kb(16)][frag = kk*2+s (4)][lane(64)][16 B]
__global__ void pack_w_kernel(const float* __restrict__ w, char* __restrict__ wp) {
  int t    = blockIdx.x * blockDim.x + threadIdx.x;  // 524288 threads
  int lane = t & 63;
  int kk   = (t >> 6) & 1;
  int kb   = (t >> 7) & 15;
  int nt   = (t >> 11) & 15;
  int e    = t >> 15;
  int k0 = kb * 32 + kk * 16 + (lane >> 5) * 8;
  int n  = nt * 32 + (lane & 31);
  const float* src = w + ((size_t)e * DIN + k0) * HID + n;
  bf16x8 hi, lo;
#pragma unroll
  for (int j = 0; j < 8; ++j) {
    float v = src[(size_t)j * HID];
    short h = f2bf(v);
    hi[j] = h;
    lo[j] = f2bf(v - bf2f(h));
  }
  char* dst = wp + (((size_t)(e * 16 + nt) * 16 + kb) << 12) + (kk << 11) + (lane << 4);
  *(bf16x8*)dst = hi;              // s=0
  *(bf16x8*)(dst + 1024) = lo;     // s=1
}

#define MFMA32(A, B, C) __builtin_amdgcn_mfma_f32_32x32x16_bf16(A, B, C, 0, 0, 0)

// load 8 B-frags (ntl 0/1 x kk 0/1 x hi/lo) for K-chunk kb_ into dst (array expr, static idx)
#define LOADB(dst, kb_) do {                                          \
    const int _k = (kb_) << 12;                                       \
    dst[0] = *(const bf16x8*)(w0 + _k);                               \
    dst[1] = *(const bf16x8*)(w0 + _k + 1024);                        \
    dst[2] = *(const bf16x8*)(w0 + _k + 2048);                        \
    dst[3] = *(const bf16x8*)(w0 + _k + 3072);                        \
    dst[4] = *(const bf16x8*)(w1 + _k);                               \
    dst[5] = *(const bf16x8*)(w1 + _k + 1024);                        \
    dst[6] = *(const bf16x8*)(w1 + _k + 2048);                        \
    dst[7] = *(const bf16x8*)(w1 + _k + 3072);                        \
  } while (0)

__global__ __launch_bounds__(512, 2) void fused_mlp_kernel(
    const char* __restrict__ xp,
    const char* __restrict__ wp1,
    const char* __restrict__ wp2,
    const float* __restrict__ b1,
    const float* __restrict__ b2,
    const float* __restrict__ w3,
    const float* __restrict__ b3,
    float* __restrict__ out)
{
  __shared__ __align__(16) char lds[IMG_BYTES];
  __shared__ float out_acc[BT];

  const int tid    = threadIdx.x;
  const int lane   = tid & 63;
  const int wid    = tid >> 6;       // 8 waves; wave owns cols [wid*64, wid*64+64)
  const int lane31 = lane & 31;
  const int hk16   = (lane >> 5) << 4;     // k-half byte offset
  const int aswz   = (lane & 15) << 4;     // A-read swizzle (row&15 == lane&15 here)

  // XCD-bijective mapping: XCD x works e=2x then e=2x+1 -> packed W L2-resident
  const int bid   = blockIdx.x;
  const int xcd   = bid & 7;
  const int slot  = bid >> 3;        // 0..255
  const int e     = (xcd << 1) | (slot >> 7);
  const int btile = slot & 127;

  // stage pre-swizzled x image (128 KB) linearly into LDS
  {
    const char* src = xp + (size_t)btile * IMG_BYTES;
#pragma unroll
    for (int it = 0; it < 16; ++it) {
      int off = (it << 13) + (tid << 4);
      *(bf16x8*)(lds + off) = *(const bf16x8*)(src + off);
    }
  }
  if (tid < BT) out_acc[tid] = b3[e];

  int arow[2];
#pragma unroll
  for (int mt = 0; mt < 2; ++mt) arow[mt] = ((mt << 5) + lane31) << 10;

  float bias1[2], bias2[2], w3v[2];
#pragma unroll
  for (int ntl = 0; ntl < 2; ++ntl) {
    int c = wid * 64 + ntl * 32 + lane31;
    bias1[ntl] = b1[e * HID + c];
    bias2[ntl] = b2[e * HID + c];
    w3v[ntl]   = w3[e * HID + c];
  }

  // per-wave B pointers: nt = wid*2 + ntl
  const char* wA0 = wp1 + (size_t)e * WP_PER_E + ((size_t)(wid * 2 + 0) << 16) + (lane << 4);
  const char* wA1 = wp1 + (size_t)e * WP_PER_E + ((size_t)(wid * 2 + 1) << 16) + (lane << 4);
  const char* wB0 = wp2 + (size_t)e * WP_PER_E + ((size_t)(wid * 2 + 0) << 16) + (lane << 4);
  const char* wB1 = wp2 + (size_t)e * WP_PER_E + ((size_t)(wid * 2 + 1) << 16) + (lane << 4);

  __syncthreads();

  f32x16 acc[2][2];

  // run one layer's K loop: acc must be zeroed by caller
  auto run_layer = [&](const char* w0, const char* w1) {
    bf16x8 Bb[2][8];
    LOADB(Bb[0], 0);
#pragma unroll
    for (int kb = 0; kb < 16; ++kb) {
      if (kb < 15) LOADB(Bb[(kb + 1) & 1], kb + 1);
      bf16x8 Ah[2][2], Al[2][2];
#pragma unroll
      for (int mt = 0; mt < 2; ++mt)
#pragma unroll
        for (int kk = 0; kk < 2; ++kk) {
          const int off = ((kb << 6) + (kk << 5) + hk16) ^ aswz;
          const char* pa = lds + arow[mt] + off;
          Ah[mt][kk] = *(const bf16x8*)pa;
          Al[mt][kk] = *(const bf16x8*)(pa + 65536);
        }
#pragma unroll
      for (int mt = 0; mt < 2; ++mt)
#pragma unroll
        for (int ntl = 0; ntl < 2; ++ntl)
#pragma unroll
          for (int kk = 0; kk < 2; ++kk) {
            const int fb = ntl * 4 + kk * 2;
            acc[mt][ntl] = MFMA32(Ah[mt][kk], Bb[kb & 1][fb],     acc[mt][ntl]);
            acc[mt][ntl] = MFMA32(Ah[mt][kk], Bb[kb & 1][fb + 1], acc[mt][ntl]);
            acc[mt][ntl] = MFMA32(Al[mt][kk], Bb[kb & 1][fb],     acc[mt][ntl]);
          }
    }
  };

#pragma unroll
  for (int mt = 0; mt < 2; ++mt)
#pragma unroll
    for (int ntl = 0; ntl < 2; ++ntl)
      acc[mt][ntl] = (f32x16)(0.f);

  // ---------------- Layer 1: h1 = relu(x@W1 + b1) ----------------
  run_layer(wA0, wA1);

  __syncthreads();   // everyone done reading x image

  // bias + relu + hi/lo split, write h1 over the x image (same swizzle)
  // C/D layout (m74/m101): col = lane&31, row = (reg&3) + 8*(reg>>2) + 4*(lane>>5)
#pragma unroll
  for (int mt = 0; mt < 2; ++mt)
#pragma unroll
    for (int ntl = 0; ntl < 2; ++ntl) {
      const int C2 = (wid * 64 + ntl * 32 + lane31) << 1;
#pragma unroll
      for (int reg = 0; reg < 16; ++reg) {
        const int R = mt * 32 + (reg & 3) + 8 * (reg >> 2) + ((lane >> 5) << 2);
        float v = acc[mt][ntl][reg] + bias1[ntl];
        v = fmaxf(v, 0.f);
        short hb = f2bf(v);
        short lb = f2bf(v - bf2f(hb));
        const int inrow = C2 ^ ((R & 15) << 4);
        *(short*)(lds + (R << 10) + inrow) = hb;
        *(short*)(lds + 65536 + (R << 10) + inrow) = lb;
      }
    }

  __syncthreads();

#pragma unroll
  for (int mt = 0; mt < 2; ++mt)
#pragma unroll
    for (int ntl = 0; ntl < 2; ++ntl)
      acc[mt][ntl] = (f32x16)(0.f);

  // ---------------- Layer 2: h2 = relu(h1@W2 + b2) ----------------
  run_layer(wB0, wB1);

  // ---------------- Layer 3: out = h2 @ W3 + b3 (in-register) ----------------
#pragma unroll
  for (int mt = 0; mt < 2; ++mt)
#pragma unroll
    for (int reg = 0; reg < 16; ++reg) {
      float p = 0.f;
#pragma unroll
      for (int ntl = 0; ntl < 2; ++ntl)
        p += fmaxf(acc[mt][ntl][reg] + bias2[ntl], 0.f) * w3v[ntl];
      // reduce over the 32-lane column group
      p += __shfl_xor(p, 1);
      p += __shfl_xor(p, 2);
      p += __shfl_xor(p, 4);
      p += __shfl_xor(p, 8);
      p += __shfl_xor(p, 16);
      if (lane31 == 0) {
        const int R = mt * 32 + (reg & 3) + 8 * (reg >> 2) + ((lane >> 5) << 2);
        atomicAdd(&out_acc[R], p);
      }
    }

  __syncthreads();
  if (tid < BT)
    out[(size_t)e * BATCH + btile * BT + tid] = out_acc[tid];
}

extern "C" void kernel_launch(void* const* d_in, const int* in_sizes, int n_in,
                              void* d_out, int out_size, void* d_ws, size_t ws_size,
                              hipStream_t stream) {
  (void)in_sizes; (void)n_in; (void)out_size; (void)ws_size;
  const float* x  = (const float*)d_in[0];
  const float* W1 = (const float*)d_in[1];
  const float* b1 = (const float*)d_in[2];
  const float* W2 = (const float*)d_in[3];
  const float* b2 = (const float*)d_in[4];
  const float* W3 = (const float*)d_in[5];
  const float* b3 = (const float*)d_in[6];

  char* xp  = (char*)d_ws;            // 16.78 MB
  char* wp1 = xp + XPACK_BYTES;       // 16.78 MB
  char* wp2 = wp1 + WP_BYTES;         // 16.78 MB

  pack_x_kernel<<<2048, 256, 0, stream>>>(x, xp);
  pack_w_kernel<<<2048, 256, 0, stream>>>(W1, wp1);
  pack_w_kernel<<<2048, 256, 0, stream>>>(W2, wp2);
  fused_mlp_kernel<<<NBLK, 512, 0, stream>>>(xp, wp1, wp2, b1, b2, W3, b3,
                                             (float*)d_out);
}

// Round 4
// 480.363 us; speedup vs baseline: 1.0260x; 1.0260x over previous
//
#include <hip/hip_runtime.h>

// EnsembleFC: out = relu(relu(x@W1+b1)@W2+b2)@W3+b3, E=16, B=8192, D=H=512, DOUT=1
// bf16 hi/lo split (3-MFMA emulated fp32), fully fused, 16x16x32 MFMA.
// R3: 16 waves/block (4 waves/SIMD TLP), conflict-free r&15 swizzle, 1-deep B dbuf.

#define E_N   16
#define DIN   512
#define HID   512
#define BATCH 8192
#define BT    64
#define NBT   (BATCH / BT)   // 128
#define NBLK  (E_N * NBT)    // 2048

typedef __attribute__((ext_vector_type(8))) short bf16x8;
typedef __attribute__((ext_vector_type(4))) float f32x4;

#define IMG_BYTES   131072                      // [2 s][64 r][1024 B], swizzled (r&15)<<4
#define XPACK_BYTES ((size_t)NBT * IMG_BYTES)   // 16.78 MB
#define WP_PER_E    (32 * 16 * 2048)            // [32 nt][16 kb][2 s][64 lane][16 B] = 1 MB
#define WP_BYTES    ((size_t)E_N * WP_PER_E)    // 16.78 MB

__device__ __forceinline__ short f2bf(float f) {
  unsigned u = __builtin_bit_cast(unsigned, f);
  u += 0x7fffu + ((u >> 16) & 1u);              // RTNE
  return (short)(u >> 16);
}
__device__ __forceinline__ float bf2f(short s) {
  unsigned u = ((unsigned)(unsigned short)s) << 16;
  return __builtin_bit_cast(float, u);
}

// ---- prep: split x into hi/lo bf16 images, swizzle (r&15)<<4 baked in ----
__global__ void pack_x_kernel(const float* __restrict__ x, char* __restrict__ xp) {
  int t  = blockIdx.x * blockDim.x + threadIdx.x;  // 524288 threads
  int b  = t >> 6;
  int c8 = (t & 63) << 3;
  const float* src = x + (size_t)b * DIN + c8;
  bf16x8 hi, lo;
#pragma unroll
  for (int j = 0; j < 8; ++j) {
    float v = src[j];
    short h = f2bf(v);
    hi[j] = h;
    lo[j] = f2bf(v - bf2f(h));
  }
  int btile = b >> 6, r = b & 63;
  char* img = xp + (size_t)btile * IMG_BYTES;
  int inrow = (c8 << 1) ^ ((r & 15) << 4);
  *(bf16x8*)(img + (r << 10) + inrow) = hi;
  *(bf16x8*)(img + 65536 + (r << 10) + inrow) = lo;
}

// ---- prep: split W into hi/lo bf16 B-fragments (16x16x32 layout) ----
// frag element: W[e][kb*32 + (lane>>4)*8 + j][nt*16 + (lane&15)]
// dst: [e][nt(32)][kb(16)][s(2)][lane(64)][16 B]
__global__ void pack_w_kernel(const float* __restrict__ w, char* __restrict__ wp) {
  int t    = blockIdx.x * blockDim.x + threadIdx.x;  // 524288 threads
  int lane = t & 63;
  int kb   = (t >> 6) & 15;
  int nt   = (t >> 10) & 31;
  int e    = t >> 15;
  int k0 = kb * 32 + (lane >> 4) * 8;
  int n  = nt * 16 + (lane & 15);
  const float* src = w + ((size_t)e * DIN + k0) * HID + n;
  bf16x8 hi, lo;
#pragma unroll
  for (int j = 0; j < 8; ++j) {
    float v = src[(size_t)j * HID];
    short h = f2bf(v);
    hi[j] = h;
    lo[j] = f2bf(v - bf2f(h));
  }
  char* dst = wp + ((size_t)((e * 32 + nt) * 16 + kb) << 11) + (lane << 4);
  *(bf16x8*)dst = hi;
  *(bf16x8*)(dst + 1024) = lo;
}

#define MFMA16(A, B, C) __builtin_amdgcn_mfma_f32_16x16x32_bf16(A, B, C, 0, 0, 0)

// load 4 B-frags (ntl 0/1 x hi/lo) for K-chunk kb_ (static idx)
#define LOADB(dst, kb_) do {                                          \
    const int _k = (kb_) << 11;                                       \
    dst[0] = *(const bf16x8*)(w0 + _k);                               \
    dst[1] = *(const bf16x8*)(w0 + _k + 1024);                        \
    dst[2] = *(const bf16x8*)(w1 + _k);                               \
    dst[3] = *(const bf16x8*)(w1 + _k + 1024);                        \
  } while (0)

__global__ __launch_bounds__(1024, 4) void fused_mlp_kernel(
    const char* __restrict__ xp,
    const char* __restrict__ wp1,
    const char* __restrict__ wp2,
    const float* __restrict__ b1,
    const float* __restrict__ b2,
    const float* __restrict__ w3,
    const float* __restrict__ b3,
    float* __restrict__ out)
{
  __shared__ __align__(16) char lds[IMG_BYTES];
  __shared__ float out_acc[BT];

  const int tid    = threadIdx.x;
  const int lane   = tid & 63;
  const int wid    = tid >> 6;       // 16 waves; wave owns cols [wid*32, wid*32+32)
  const int lane15 = lane & 15;
  const int h4     = (lane >> 4) << 4;     // k-quarter byte offset
  const int aswz   = lane15 << 4;          // A-read swizzle (row&15 == lane&15)

  // XCD-bijective mapping: XCD x works e=2x then e=2x+1 -> packed W L2-resident
  const int bid   = blockIdx.x;
  const int xcd   = bid & 7;
  const int slot  = bid >> 3;        // 0..255
  const int e     = (xcd << 1) | (slot >> 7);
  const int btile = slot & 127;

  // stage pre-swizzled x image (128 KB) linearly into LDS
  {
    const char* src = xp + (size_t)btile * IMG_BYTES;
#pragma unroll
    for (int it = 0; it < 8; ++it) {
      int off = (it << 14) + (tid << 4);
      *(bf16x8*)(lds + off) = *(const bf16x8*)(src + off);
    }
  }
  if (tid < BT) out_acc[tid] = b3[e];

  int rb[4];
#pragma unroll
  for (int mt = 0; mt < 4; ++mt) rb[mt] = ((mt << 4) + lane15) << 10;

  float bias1[2], bias2[2], w3v[2];
#pragma unroll
  for (int ntl = 0; ntl < 2; ++ntl) {
    int c = wid * 32 + ntl * 16 + lane15;
    bias1[ntl] = b1[e * HID + c];
    bias2[ntl] = b2[e * HID + c];
    w3v[ntl]   = w3[e * HID + c];
  }

  // per-wave B pointers: nt = wid*2 + ntl
  const char* wA0 = wp1 + (size_t)e * WP_PER_E + ((size_t)(wid * 2 + 0) << 15) + (lane << 4);
  const char* wA1 = wp1 + (size_t)e * WP_PER_E + ((size_t)(wid * 2 + 1) << 15) + (lane << 4);
  const char* wB0 = wp2 + (size_t)e * WP_PER_E + ((size_t)(wid * 2 + 0) << 15) + (lane << 4);
  const char* wB1 = wp2 + (size_t)e * WP_PER_E + ((size_t)(wid * 2 + 1) << 15) + (lane << 4);

  __syncthreads();

  f32x4 acc[4][2];

  // one layer's K loop; acc must be zeroed by caller
  auto run_layer = [&](const char* w0, const char* w1) {
    bf16x8 Bb[2][4];
    LOADB(Bb[0], 0);
#pragma unroll
    for (int kb = 0; kb < 16; ++kb) {
      if (kb < 15) LOADB(Bb[(kb + 1) & 1], kb + 1);
      bf16x8 Ah[4], Al[4];
      const int ca = ((kb << 6) + h4) ^ aswz;
#pragma unroll
      for (int mt = 0; mt < 4; ++mt) {
        const char* pa = lds + rb[mt] + ca;
        Ah[mt] = *(const bf16x8*)pa;
        Al[mt] = *(const bf16x8*)(pa + 65536);
      }
#pragma unroll
      for (int mt = 0; mt < 4; ++mt)
#pragma unroll
        for (int ntl = 0; ntl < 2; ++ntl) {
          const bf16x8 bh = Bb[kb & 1][ntl * 2];
          const bf16x8 bl = Bb[kb & 1][ntl * 2 + 1];
          acc[mt][ntl] = MFMA16(Ah[mt], bh, acc[mt][ntl]);
          acc[mt][ntl] = MFMA16(Ah[mt], bl, acc[mt][ntl]);
          acc[mt][ntl] = MFMA16(Al[mt], bh, acc[mt][ntl]);
        }
    }
  };

#pragma unroll
  for (int mt = 0; mt < 4; ++mt)
#pragma unroll
    for (int ntl = 0; ntl < 2; ++ntl)
      acc[mt][ntl] = (f32x4){0.f, 0.f, 0.f, 0.f};

  // ---------------- Layer 1: h1 = relu(x@W1 + b1) ----------------
  run_layer(wA0, wA1);

  __syncthreads();   // everyone done reading x image

  // bias + relu + hi/lo split, write h1 over the x image (same swizzle)
  // C/D layout (m89): col = lane&15, row = (lane>>4)*4 + q
#pragma unroll
  for (int mt = 0; mt < 4; ++mt)
#pragma unroll
    for (int ntl = 0; ntl < 2; ++ntl) {
      const int C2 = (wid * 32 + ntl * 16 + lane15) << 1;
#pragma unroll
      for (int q = 0; q < 4; ++q) {
        const int R = mt * 16 + (lane >> 4) * 4 + q;
        float v = acc[mt][ntl][q] + bias1[ntl];
        v = fmaxf(v, 0.f);
        short hb = f2bf(v);
        short lb = f2bf(v - bf2f(hb));
        const int inrow = C2 ^ ((R & 15) << 4);
        *(short*)(lds + (R << 10) + inrow) = hb;
        *(short*)(lds + 65536 + (R << 10) + inrow) = lb;
      }
    }

  __syncthreads();

#pragma unroll
  for (int mt = 0; mt < 4; ++mt)
#pragma unroll
    for (int ntl = 0; ntl < 2; ++ntl)
      acc[mt][ntl] = (f32x4){0.f, 0.f, 0.f, 0.f};

  // ---------------- Layer 2: h2 = relu(h1@W2 + b2) ----------------
  run_layer(wB0, wB1);

  // ---------------- Layer 3: out = h2 @ W3 + b3 (in-register) ----------------
#pragma unroll
  for (int mt = 0; mt < 4; ++mt)
#pragma unroll
    for (int q = 0; q < 4; ++q) {
      float p = 0.f;
#pragma unroll
      for (int ntl = 0; ntl < 2; ++ntl)
        p += fmaxf(acc[mt][ntl][q] + bias2[ntl], 0.f) * w3v[ntl];
      // reduce over the 16-lane column group
      p += __shfl_xor(p, 1);
      p += __shfl_xor(p, 2);
      p += __shfl_xor(p, 4);
      p += __shfl_xor(p, 8);
      if (lane15 == 0)
        atomicAdd(&out_acc[mt * 16 + (lane >> 4) * 4 + q], p);
    }

  __syncthreads();
  if (tid < BT)
    out[(size_t)e * BATCH + btile * BT + tid] = out_acc[tid];
}

extern "C" void kernel_launch(void* const* d_in, const int* in_sizes, int n_in,
                              void* d_out, int out_size, void* d_ws, size_t ws_size,
                              hipStream_t stream) {
  (void)in_sizes; (void)n_in; (void)out_size; (void)ws_size;
  const float* x  = (const float*)d_in[0];
  const float* W1 = (const float*)d_in[1];
  const float* b1 = (const float*)d_in[2];
  const float* W2 = (const float*)d_in[3];
  const float* b2 = (const float*)d_in[4];
  const float* W3 = (const float*)d_in[5];
  const float* b3 = (const float*)d_in[6];

  char* xp  = (char*)d_ws;            // 16.78 MB
  char* wp1 = xp + XPACK_BYTES;       // 16.78 MB
  char* wp2 = wp1 + WP_BYTES;         // 16.78 MB

  pack_x_kernel<<<2048, 256, 0, stream>>>(x, xp);
  pack_w_kernel<<<2048, 256, 0, stream>>>(W1, wp1);
  pack_w_kernel<<<2048, 256, 0, stream>>>(W2, wp2);
  fused_mlp_kernel<<<NBLK, 1024, 0, stream>>>(xp, wp1, wp2, b1, b2, W3, b3,
                                              (float*)d_out);
}